// Round 7
// baseline (939.574 us; speedup 1.0000x reference)
//
#include <hip/hip_runtime.h>
#include <hip/hip_bf16.h>
#include <hip/hip_fp16.h>

#define NN 100000
#define NE 1600000
#define D_IN 7
#define H1 64
#define H2 32
#define NG 64
#define TE 2048          // edges per bin tile
#define NTILE 782        // ceil(NE/TE)
#define BSH 9            // bucket = dst >> 9  (512 nodes/bucket)
#define NBUK 196         // ceil(NN/512)
#define CAP 10240        // slots per bucket (mean 8192, +22 sigma)

typedef _Float16 f16x8 __attribute__((ext_vector_type(8)));
typedef float f32x4 __attribute__((ext_vector_type(4)));

union g16 { f16x8 v; __half2 h[4]; };

// ---------------- mean pool over sorted batch + bucket-cursor init (block NG) ----------------
__device__ int lower_bound_i(const int* a, int n, int v) {
    int lo = 0, hi = n;
    while (lo < hi) { int mid = (lo + hi) >> 1; if (a[mid] < v) lo = mid + 1; else hi = mid; }
    return lo;
}

__global__ void k_pi(const float* __restrict__ x, const int* __restrict__ batch,
                     float* __restrict__ outp, int* __restrict__ bucket_cursor) {
    int g = blockIdx.x, t = threadIdx.x;
    if (g == NG) {                       // fused k_init
        if (t < 256) bucket_cursor[t] = t * CAP;
        return;
    }
    __shared__ int bounds[2];
    __shared__ float red[256 * D_IN];
    if (t == 0) {
        bounds[0] = lower_bound_i(batch, NN, g);
        bounds[1] = lower_bound_i(batch, NN, g + 1);
    }
    __syncthreads();
    int s = bounds[0], e = bounds[1];
    float acc[D_IN];
#pragma unroll
    for (int k = 0; k < D_IN; k++) acc[k] = 0.f;
    for (int n = s + t; n < e; n += 256) {
#pragma unroll
        for (int k = 0; k < D_IN; k++) acc[k] += x[n * D_IN + k];
    }
#pragma unroll
    for (int k = 0; k < D_IN; k++) red[t * D_IN + k] = acc[k];
    __syncthreads();
    if (t < D_IN) {
        float sum = 0.f;
        for (int i = 0; i < 256; i++) sum += red[i * D_IN + t];
        float cnt = (float)(e - s);
        outp[g * D_IN + t] = sum / fmaxf(cnt, 1.f);
    }
}

// ---------------- bin edges into fixed-capacity buckets (coalesced flush) ----------------
__global__ __launch_bounds__(256) void k_bin(const int* __restrict__ src,
                                             const int* __restrict__ dst,
                                             int* __restrict__ bucket_cursor,
                                             int* __restrict__ staging) {
    __shared__ int hist[NBUK];
    __shared__ int startx[NBUK];
    __shared__ int runb[NBUK];
    __shared__ int cur[NBUK];
    __shared__ int wsum[4];
    __shared__ int2 pairs[TE];
    int t = threadIdx.x;
    int base = blockIdx.x * TE;
    int tile_cnt = min(TE, NE - base);
    for (int i = t; i < NBUK; i += 256) hist[i] = 0;
    __syncthreads();
    int myd[TE / 256], mys[TE / 256];
#pragma unroll
    for (int k = 0; k < TE / 256; k++) {
        int i = base + k * 256 + t;
        if (i < NE) {
            myd[k] = dst[i]; mys[k] = src[i];
            atomicAdd(&hist[myd[k] >> BSH], 1);
        } else myd[k] = -1;
    }
    __syncthreads();
    int hv = (t < NBUK) ? hist[t] : 0;
    // wave-shuffle inclusive scan over 256 threads (4 waves)
    int lane = t & 63, wv = t >> 6;
    int sv = hv;
#pragma unroll
    for (int off = 1; off < 64; off <<= 1) {
        int n = __shfl_up(sv, off, 64);
        if (lane >= off) sv += n;
    }
    if (lane == 63) wsum[wv] = sv;
    __syncthreads();
    int wbase = 0;
#pragma unroll
    for (int i = 0; i < 4; i++) wbase += (i < wv) ? wsum[i] : 0;
    if (t < NBUK) {
        int ex = wbase + sv - hv;        // exclusive scan
        startx[t] = ex;
        cur[t] = ex;
        if (hv > 0) runb[t] = atomicAdd(&bucket_cursor[t], hv);
    }
    __syncthreads();
#pragma unroll
    for (int k = 0; k < TE / 256; k++) {
        if (myd[k] >= 0) {
            int b = myd[k] >> BSH;
            int slot = atomicAdd(&cur[b], 1);
            pairs[slot] = make_int2(myd[k], mys[k]);
        }
    }
    __syncthreads();
    for (int i = t; i < tile_cnt; i += 256) {   // pack (local<<17)|src at flush
        int2 p = pairs[i];
        int b = p.x >> BSH;
        staging[runb[b] + (i - startx[b])] = ((p.x & 511) << 17) | p.y;
    }
}

// ---------------- per-bucket CSR finalize: rowinfo, dis, dense scatter (packed), xd8 = dis*x ----------------
__global__ __launch_bounds__(512) void k_build(const int* __restrict__ staging,
                                               const int* __restrict__ bucket_cursor,
                                               int2* __restrict__ rowinfo,
                                               float* __restrict__ dis,
                                               int* __restrict__ csr,
                                               const float* __restrict__ x,
                                               float* __restrict__ xd8) {
    __shared__ int cnt[512];
    __shared__ int cur[512];
    __shared__ int wsum[8];
    int t = threadIdx.x;
    int nbase = blockIdx.x << BSH;
    int ebase = blockIdx.x * CAP;
    int eend = bucket_cursor[blockIdx.x];   // ebase + count
    cnt[t] = 0;
    __syncthreads();
    for (int i = ebase + t; i < eend; i += 512)
        atomicAdd(&cnt[staging[i] >> 17], 1);
    __syncthreads();
    int v = cnt[t];
    // wave-shuffle inclusive scan over 512 threads (8 waves)
    int lane = t & 63, wv = t >> 6;
    int sv = v;
#pragma unroll
    for (int off = 1; off < 64; off <<= 1) {
        int n = __shfl_up(sv, off, 64);
        if (lane >= off) sv += n;
    }
    if (lane == 63) wsum[wv] = sv;
    __syncthreads();
    int wbase = 0;
#pragma unroll
    for (int i = 0; i < 8; i++) wbase += (i < wv) ? wsum[i] : 0;
    int excl = wbase + sv - v;
    cur[t] = excl;
    int node = nbase + t;
    if (node < NN) {
        rowinfo[node] = make_int2(ebase + excl, v);
        float d = rsqrtf((float)v + 1.0f);
        dis[node] = d;
        const float* xr = x + (size_t)node * D_IN;
        float4 w0 = make_float4(d * xr[0], d * xr[1], d * xr[2], d * xr[3]);
        float4 w1 = make_float4(d * xr[4], d * xr[5], d * xr[6], 0.f);
        float4* xo = (float4*)(xd8 + (size_t)node * 8);
        xo[0] = w0; xo[1] = w1;
    }
    __syncthreads();
    for (int i = ebase + t; i < eend; i += 512) {
        int p = staging[i];
        int pos = ebase + atomicAdd(&cur[p >> 17], 1);
        csr[pos] = p;            // keep full packed (local<<17)|src — sorted by local
    }
}

// ---------------- layer-1: edge-parallel LDS-atomic aggregation + fused @W1 epilogue ----------------
// Block = (bucket, quarter): 128 nodes, contiguous csr slice.  Edges independent:
// 1 thread/edge, 32B xd8 gather + 7 fp32 LDS atomicAdds.  Epilogue: 2 thr/node, 32 out-ch.
__global__ __launch_bounds__(256) void k_agg1b(const int2* __restrict__ rowinfo,
                                               const int* __restrict__ bucket_cursor,
                                               const float* __restrict__ dis,
                                               const int* __restrict__ csr,
                                               const float* __restrict__ xd8,
                                               const float* __restrict__ W1,
                                               const float* __restrict__ b1,
                                               __half* __restrict__ h1h) {
    __shared__ float acc[128 * 9];         // stride 9: bank spread
    __shared__ float sW[D_IN * H1];
    __shared__ float sb[H1];
    int t = threadIdx.x;
    int b = blockIdx.x >> 2, q = blockIdx.x & 3;
    int nbase = (b << BSH) + (q << 7);
    for (int i = t; i < 128 * 9; i += 256) acc[i] = 0.f;
    for (int i = t; i < D_IN * H1; i += 256) sW[i] = W1[i];
    if (t < H1) sb[t] = b1[t];
    int eend_b = bucket_cursor[b];
    int n1 = nbase + 128;
    int estart = (nbase < NN) ? rowinfo[nbase].x : eend_b;
    int eendq  = (q == 3 || n1 >= NN) ? eend_b : rowinfo[n1].x;
    __syncthreads();
    for (int e = estart + t; e < eendq; e += 256) {
        int p = csr[e];
        int src = p & 0x1FFFF;
        int l7 = (p >> 17) & 127;
        float4 r0 = *(const float4*)(xd8 + (size_t)src * 8);
        float4 r1 = *(const float4*)(xd8 + (size_t)src * 8 + 4);
        float* a = &acc[l7 * 9];
        atomicAdd(a + 0, r0.x); atomicAdd(a + 1, r0.y);
        atomicAdd(a + 2, r0.z); atomicAdd(a + 3, r0.w);
        atomicAdd(a + 4, r1.x); atomicAdd(a + 5, r1.y);
        atomicAdd(a + 6, r1.z);            // ch7 of xd8 is always 0 — skip
    }
    __syncthreads();
    int ln = t >> 1, hf = t & 1;
    int node = nbase + ln;
    if (node < NN) {
        float dn = dis[node];
        const float* xr = xd8 + (size_t)node * 8;
        float s[D_IN];
#pragma unroll
        for (int k = 0; k < D_IN; k++) s[k] = dn * (acc[ln * 9 + k] + xr[k]);
        union { __half h[32]; float4 f[4]; } u;
#pragma unroll
        for (int j = 0; j < 32; j++) {
            int hh = hf * 32 + j;
            float a = sb[hh];
#pragma unroll
            for (int k = 0; k < D_IN; k++) a += s[k] * sW[k * H1 + hh];
            u.h[j] = __float2half(dn * fmaxf(a, 0.f));
        }
        float4* d4 = (float4*)(h1h + (size_t)node * 64 + hf * 32);
        d4[0] = u.f[0]; d4[1] = u.f[1]; d4[2] = u.f[2]; d4[3] = u.f[3];
    }
}

// ---------------- layer-2: edge-parallel LDS-atomic aggregation (fp32) ----------------
// Block = (bucket, quarter): acc[128][65] fp32 (33.3KB, padded stride = conflict-free).
// 8 lanes/edge: 16B h1h gather each (full 128B row per edge) + 8 fp32 LDS atomicAdds.
// All edges independent -> MLP limited only by occupancy (4 blocks x 8 waves / CU).
__global__ __launch_bounds__(512) void k_agg2b(const int2* __restrict__ rowinfo,
                                               const int* __restrict__ bucket_cursor,
                                               const float* __restrict__ dis,
                                               const int* __restrict__ csr,
                                               const __half* __restrict__ h1h,
                                               __half* __restrict__ sAgg) {
    __shared__ float acc[128 * 65];
    int t = threadIdx.x;
    int b = blockIdx.x >> 2, q = blockIdx.x & 3;
    int nbase = (b << BSH) + (q << 7);
    for (int i = t; i < 128 * 65; i += 512) acc[i] = 0.f;
    int eend_b = bucket_cursor[b];
    int n1 = nbase + 128;
    int estart = (nbase < NN) ? rowinfo[nbase].x : eend_b;
    int eendq  = (q == 3 || n1 >= NN) ? eend_b : rowinfo[n1].x;
    __syncthreads();
    int grp = t >> 3, sl = t & 7;
    for (int e = estart + grp; e < eendq; e += 64) {
        int p = csr[e];                    // 8 lanes same addr -> broadcast
        int src = p & 0x1FFFF;
        int l7 = (p >> 17) & 127;
        g16 r;
        r.v = *(const f16x8*)(h1h + (size_t)src * 64 + sl * 8);
        float2 f0 = __half22float2(r.h[0]);
        float2 f1 = __half22float2(r.h[1]);
        float2 f2 = __half22float2(r.h[2]);
        float2 f3 = __half22float2(r.h[3]);
        float* a = &acc[l7 * 65 + sl * 8];
        atomicAdd(a + 0, f0.x); atomicAdd(a + 1, f0.y);
        atomicAdd(a + 2, f1.x); atomicAdd(a + 3, f1.y);
        atomicAdd(a + 4, f2.x); atomicAdd(a + 5, f2.y);
        atomicAdd(a + 6, f3.x); atomicAdd(a + 7, f3.y);
    }
    __syncthreads();
    int ln = t >> 2, qq = t & 3;           // 4 threads/node, 16 ch each
    int node = nbase + ln;
    if (node < NN) {
        float dn = dis[node];
        g16 s0, s1, o0, o1;
        s0.v = *(const f16x8*)(h1h + (size_t)node * 64 + qq * 16);
        s1.v = *(const f16x8*)(h1h + (size_t)node * 64 + qq * 16 + 8);
        const float* a = &acc[ln * 65 + qq * 16];
#pragma unroll
        for (int j = 0; j < 4; j++) {
            float2 sf = __half22float2(s0.h[j]);
            __half2 h;
            h.x = __float2half(dn * (a[2 * j]     + sf.x));
            h.y = __float2half(dn * (a[2 * j + 1] + sf.y));
            o0.h[j] = h;
        }
#pragma unroll
        for (int j = 0; j < 4; j++) {
            float2 sf = __half22float2(s1.h[j]);
            __half2 h;
            h.x = __float2half(dn * (a[8 + 2 * j]     + sf.x));
            h.y = __float2half(dn * (a[8 + 2 * j + 1] + sf.y));
            o1.h[j] = h;
        }
        *(f16x8*)(sAgg + (size_t)node * 64 + qq * 16)     = o0.v;
        *(f16x8*)(sAgg + (size_t)node * 64 + qq * 16 + 8) = o1.v;
    }
}

// ---------------- y = sAgg @ (W2‖W3) via MFMA + full epilogue (mu/lv/z) ----------------
// Block = 64 rows, 4 waves x 16 rows.  A read row-major (verified round-0 pattern).
__global__ __launch_bounds__(256) void k_mm23(const __half* __restrict__ sAgg,
                                              const float* __restrict__ W2,
                                              const float* __restrict__ W3,
                                              const float* __restrict__ b2,
                                              const float* __restrict__ b3,
                                              const float* __restrict__ eps,
                                              float* __restrict__ out_z,
                                              float* __restrict__ out_mu,
                                              float* __restrict__ out_lv) {
    __shared__ __align__(16) _Float16 sW[64 * 80];   // Wcat [col][k], k-stride 80
    int t = threadIdx.x;
    for (int i = t; i < 64 * 64; i += 256) {
        int c = i >> 6, k = i & 63;
        float w = (c < 32) ? W2[k * H2 + c] : W3[k * H2 + (c - 32)];
        sW[c * 80 + k] = (_Float16)w;
    }
    __syncthreads();
    int lane = t & 63;
    int wv = t >> 6;
    int sub = lane >> 4, l15 = lane & 15;
    int c15 = l15, k8 = sub;
    int r0 = blockIdx.x * 64 + wv * 16;
    int rowc = min(r0 + c15, NN - 1);
    f16x8 a0 = *(const f16x8*)(sAgg + (size_t)rowc * 64 + k8 * 8);
    f16x8 a1 = *(const f16x8*)(sAgg + (size_t)rowc * 64 + 32 + k8 * 8);
    const _Float16* wb = sW + (size_t)c15 * 80 + k8 * 8;
    f16x8 b00 = *(const f16x8*)(wb);
    f16x8 b01 = *(const f16x8*)(wb + 32);
    f16x8 b10 = *(const f16x8*)(wb + 16 * 80);
    f16x8 b11 = *(const f16x8*)(wb + 16 * 80 + 32);
    f16x8 b20 = *(const f16x8*)(wb + 32 * 80);
    f16x8 b21 = *(const f16x8*)(wb + 32 * 80 + 32);
    f16x8 b30 = *(const f16x8*)(wb + 48 * 80);
    f16x8 b31 = *(const f16x8*)(wb + 48 * 80 + 32);
    f32x4 ac0 = {0.f, 0.f, 0.f, 0.f};
    f32x4 ac1 = ac0, ac2 = ac0, ac3 = ac0;
    ac0 = __builtin_amdgcn_mfma_f32_16x16x32_f16(a0, b00, ac0, 0, 0, 0);
    ac0 = __builtin_amdgcn_mfma_f32_16x16x32_f16(a1, b01, ac0, 0, 0, 0);
    ac1 = __builtin_amdgcn_mfma_f32_16x16x32_f16(a0, b10, ac1, 0, 0, 0);
    ac1 = __builtin_amdgcn_mfma_f32_16x16x32_f16(a1, b11, ac1, 0, 0, 0);
    ac2 = __builtin_amdgcn_mfma_f32_16x16x32_f16(a0, b20, ac2, 0, 0, 0);
    ac2 = __builtin_amdgcn_mfma_f32_16x16x32_f16(a1, b21, ac2, 0, 0, 0);
    ac3 = __builtin_amdgcn_mfma_f32_16x16x32_f16(a0, b30, ac3, 0, 0, 0);
    ac3 = __builtin_amdgcn_mfma_f32_16x16x32_f16(a1, b31, ac3, 0, 0, 0);
    float bb2a = b2[c15], bb2b = b2[c15 + 16];
    float bb3a = b3[c15], bb3b = b3[c15 + 16];
    int srow = r0 + k8 * 4;                // C/D: col=lane&15, row=(lane>>4)*4+reg
#pragma unroll
    for (int i = 0; i < 4; i++) {
        int r = srow + i;
        if (r < NN) {
            float mu0 = fmaxf(ac0[i] + bb2a, 0.f);
            float mu1 = fmaxf(ac1[i] + bb2b, 0.f);
            float lv0 = fmaxf(ac2[i] + bb3a, 0.f);
            float lv1 = fmaxf(ac3[i] + bb3b, 0.f);
            size_t o0 = (size_t)r * 32 + c15;
            float e0 = eps[o0], e1 = eps[o0 + 16];
            out_mu[o0]      = mu0;
            out_mu[o0 + 16] = mu1;
            out_lv[o0]      = lv0;
            out_lv[o0 + 16] = lv1;
            out_z[o0]       = e0 * __expf(lv0) + mu0;
            out_z[o0 + 16]  = e1 * __expf(lv1) + mu1;
        }
    }
}

extern "C" void kernel_launch(void* const* d_in, const int* in_sizes, int n_in,
                              void* d_out, int out_size, void* d_ws, size_t ws_size,
                              hipStream_t stream) {
    const float* x   = (const float*)d_in[0];
    const int*   ei  = (const int*)d_in[1];   // [2, E]
    const int*   bat = (const int*)d_in[2];
    const float* W1  = (const float*)d_in[3];
    const float* b1  = (const float*)d_in[4];
    const float* W2  = (const float*)d_in[5];
    const float* b2  = (const float*)d_in[6];
    const float* W3  = (const float*)d_in[7];
    const float* b3  = (const float*)d_in[8];
    const float* eps = (const float*)d_in[9];

    const int* src = ei;
    const int* dst = ei + NE;

    float* out = (float*)d_out;
    float* out_z    = out;                               // [N,32]
    float* out_pool = out + (size_t)NN * H2;             // [G,7]
    float* out_mu   = out_pool + NG * D_IN;              // [N,32]
    float* out_lv   = out_mu + (size_t)NN * H2;          // [N,32]

    // workspace layout (16B-aligned segments)
    int*    bucket_cursor = (int*)d_ws;                          // 256
    int2*   rowinfo       = (int2*)(bucket_cursor + 256);        // NN (start,cnt)
    float*  dis           = (float*)(rowinfo + NN);              // NN
    int*    staging       = (int*)(dis + NN);                    // NBUK*CAP packed ints
    int*    csr           = staging + (size_t)NBUK * CAP;        // NBUK*CAP packed ints
    __half* h1h           = (__half*)(csr + (size_t)NBUK * CAP); // NN*64 halves row-major
    float*  xd8           = (float*)(h1h + (size_t)NN * H1);     // NN*8 fp32
    __half* sAgg          = (__half*)(xd8 + (size_t)NN * 8);     // NN*64 halves row-major

    k_pi    <<<NG + 1, 256, 0, stream>>>(x, bat, out_pool, bucket_cursor);
    k_bin   <<<NTILE, 256, 0, stream>>>(src, dst, bucket_cursor, staging);
    k_build <<<NBUK, 512, 0, stream>>>(staging, bucket_cursor, rowinfo, dis, csr, x, xd8);
    k_agg1b <<<NBUK * 4, 256, 0, stream>>>(rowinfo, bucket_cursor, dis, csr, xd8,
                                           W1, b1, h1h);
    k_agg2b <<<NBUK * 4, 512, 0, stream>>>(rowinfo, bucket_cursor, dis, csr, h1h, sAgg);
    k_mm23  <<<(NN + 63) / 64, 256, 0, stream>>>(sAgg, W2, W3, b2, b3, eps,
                                                 out_z, out_mu, out_lv);
}

// Round 8
// 205.292 us; speedup vs baseline: 4.5768x; 4.5768x over previous
//
#include <hip/hip_runtime.h>
#include <hip/hip_bf16.h>
#include <hip/hip_fp16.h>

#define NN 100000
#define NE 1600000
#define D_IN 7
#define H1 64
#define H2 32
#define NG 64
#define TE 2048          // edges per bin tile
#define NTILE 782        // ceil(NE/TE)
#define BSH 9            // bucket = dst >> 9  (512 nodes/bucket)
#define NBUK 196         // ceil(NN/512)
#define CAP 10240        // slots per bucket (mean 8192, +22 sigma)

typedef _Float16 f16x8 __attribute__((ext_vector_type(8)));
typedef float f32x4 __attribute__((ext_vector_type(4)));

// ---------------- mean pool over sorted batch + bucket-cursor init (block NG) ----------------
__device__ int lower_bound_i(const int* a, int n, int v) {
    int lo = 0, hi = n;
    while (lo < hi) { int mid = (lo + hi) >> 1; if (a[mid] < v) lo = mid + 1; else hi = mid; }
    return lo;
}

__global__ void k_pi(const float* __restrict__ x, const int* __restrict__ batch,
                     float* __restrict__ outp, int* __restrict__ bucket_cursor) {
    int g = blockIdx.x, t = threadIdx.x;
    if (g == NG) {                       // fused k_init
        if (t < 256) bucket_cursor[t] = t * CAP;
        return;
    }
    __shared__ int bounds[2];
    __shared__ float red[256 * D_IN];
    if (t == 0) {
        bounds[0] = lower_bound_i(batch, NN, g);
        bounds[1] = lower_bound_i(batch, NN, g + 1);
    }
    __syncthreads();
    int s = bounds[0], e = bounds[1];
    float acc[D_IN];
#pragma unroll
    for (int k = 0; k < D_IN; k++) acc[k] = 0.f;
    for (int n = s + t; n < e; n += 256) {
#pragma unroll
        for (int k = 0; k < D_IN; k++) acc[k] += x[n * D_IN + k];
    }
#pragma unroll
    for (int k = 0; k < D_IN; k++) red[t * D_IN + k] = acc[k];
    __syncthreads();
    if (t < D_IN) {
        float sum = 0.f;
        for (int i = 0; i < 256; i++) sum += red[i * D_IN + t];
        float cnt = (float)(e - s);
        outp[g * D_IN + t] = sum / fmaxf(cnt, 1.f);
    }
}

// ---------------- bin edges into fixed-capacity buckets (coalesced flush) ----------------
__global__ __launch_bounds__(256) void k_bin(const int* __restrict__ src,
                                             const int* __restrict__ dst,
                                             int* __restrict__ bucket_cursor,
                                             int* __restrict__ staging) {
    __shared__ int hist[NBUK];
    __shared__ int startx[NBUK];
    __shared__ int runb[NBUK];
    __shared__ int cur[NBUK];
    __shared__ int wsum[4];
    __shared__ int2 pairs[TE];
    int t = threadIdx.x;
    int base = blockIdx.x * TE;
    int tile_cnt = min(TE, NE - base);
    for (int i = t; i < NBUK; i += 256) hist[i] = 0;
    __syncthreads();
    int myd[TE / 256], mys[TE / 256];
#pragma unroll
    for (int k = 0; k < TE / 256; k++) {
        int i = base + k * 256 + t;
        if (i < NE) {
            myd[k] = dst[i]; mys[k] = src[i];
            atomicAdd(&hist[myd[k] >> BSH], 1);
        } else myd[k] = -1;
    }
    __syncthreads();
    int hv = (t < NBUK) ? hist[t] : 0;
    // wave-shuffle inclusive scan over 256 threads (4 waves)
    int lane = t & 63, wv = t >> 6;
    int sv = hv;
#pragma unroll
    for (int off = 1; off < 64; off <<= 1) {
        int n = __shfl_up(sv, off, 64);
        if (lane >= off) sv += n;
    }
    if (lane == 63) wsum[wv] = sv;
    __syncthreads();
    int wbase = 0;
#pragma unroll
    for (int i = 0; i < 4; i++) wbase += (i < wv) ? wsum[i] : 0;
    if (t < NBUK) {
        int ex = wbase + sv - hv;        // exclusive scan
        startx[t] = ex;
        cur[t] = ex;
        if (hv > 0) runb[t] = atomicAdd(&bucket_cursor[t], hv);
    }
    __syncthreads();
#pragma unroll
    for (int k = 0; k < TE / 256; k++) {
        if (myd[k] >= 0) {
            int b = myd[k] >> BSH;
            int slot = atomicAdd(&cur[b], 1);
            pairs[slot] = make_int2(myd[k], mys[k]);
        }
    }
    __syncthreads();
    for (int i = t; i < tile_cnt; i += 256) {   // pack (local<<17)|src at flush
        int2 p = pairs[i];
        int b = p.x >> BSH;
        staging[runb[b] + (i - startx[b])] = ((p.x & 511) << 17) | p.y;
    }
}

// ---------------- per-bucket CSR finalize: rowinfo, dis, dense scatter, xd8 = dis*x ----------------
__global__ __launch_bounds__(512) void k_build(const int* __restrict__ staging,
                                               const int* __restrict__ bucket_cursor,
                                               int2* __restrict__ rowinfo,
                                               float* __restrict__ dis,
                                               int* __restrict__ csr,
                                               const float* __restrict__ x,
                                               float* __restrict__ xd8) {
    __shared__ int cnt[512];
    __shared__ int cur[512];
    __shared__ int wsum[8];
    int t = threadIdx.x;
    int nbase = blockIdx.x << BSH;
    int ebase = blockIdx.x * CAP;
    int eend = bucket_cursor[blockIdx.x];   // ebase + count
    cnt[t] = 0;
    __syncthreads();
    for (int i = ebase + t; i < eend; i += 512)
        atomicAdd(&cnt[staging[i] >> 17], 1);
    __syncthreads();
    int v = cnt[t];
    // wave-shuffle inclusive scan over 512 threads (8 waves)
    int lane = t & 63, wv = t >> 6;
    int sv = v;
#pragma unroll
    for (int off = 1; off < 64; off <<= 1) {
        int n = __shfl_up(sv, off, 64);
        if (lane >= off) sv += n;
    }
    if (lane == 63) wsum[wv] = sv;
    __syncthreads();
    int wbase = 0;
#pragma unroll
    for (int i = 0; i < 8; i++) wbase += (i < wv) ? wsum[i] : 0;
    int excl = wbase + sv - v;
    cur[t] = excl;
    int node = nbase + t;
    if (node < NN) {
        rowinfo[node] = make_int2(ebase + excl, v);
        float d = rsqrtf((float)v + 1.0f);
        dis[node] = d;
        const float* xr = x + (size_t)node * D_IN;
        float4 w0 = make_float4(d * xr[0], d * xr[1], d * xr[2], d * xr[3]);
        float4 w1 = make_float4(d * xr[4], d * xr[5], d * xr[6], 0.f);
        float4* xo = (float4*)(xd8 + (size_t)node * 8);
        xo[0] = w0; xo[1] = w1;
    }
    __syncthreads();
    for (int i = ebase + t; i < eend; i += 512) {
        int p = staging[i];
        int pos = ebase + atomicAdd(&cur[p >> 17], 1);
        csr[pos] = p & 0x1FFFF;   // stores confined to bucket's ~40KB csr window
    }
}

// ---------------- fused layer-1: aggregate xd8 (fp32, L2-resident) then @W1 + bias/relu/dis ----------------
// agg(x @ W1) == agg(x) @ W1.  4 lanes/node, 16 nodes/wave, 64 nodes/block.
// Inner loop: explicit 16-deep register pipeline (idx array -> load array -> accumulate).
__global__ __launch_bounds__(256) void k_aggx(const int2* __restrict__ rowinfo,
                                              const float* __restrict__ dis,
                                              const int* __restrict__ csr,
                                              const float* __restrict__ xd8,
                                              const float* __restrict__ W1,
                                              const float* __restrict__ b1,
                                              __half* __restrict__ h1h) {
    __shared__ float sW[D_IN * H1];
    __shared__ float sb[H1];
    __shared__ float sAx[64 * 9];          // 64 local nodes x 8ch, padded to 9
    int t = threadIdx.x;
    for (int i = t; i < D_IN * H1; i += 256) sW[i] = W1[i];
    if (t < H1) sb[t] = b1[t];
    int ll = t & 3;                        // lane within node (2 channels each)
    int ln = t >> 2;                       // local node 0..63
    int node = blockIdx.x * 64 + ln;
    int nodec = min(node, NN - 1);
    int2 ri = rowinfo[nodec];
    int start = ri.x, c = ri.y;
    int cpos = start + max(c - 1, 0);
    int cmax = c;                          // wave-max degree over 16 nodes
    cmax = max(cmax, __shfl_xor(cmax, 4, 64));
    cmax = max(cmax, __shfl_xor(cmax, 8, 64));
    cmax = max(cmax, __shfl_xor(cmax, 16, 64));
    cmax = max(cmax, __shfl_xor(cmax, 32, 64));
    const float2* xb = (const float2*)xd8;
    float2 acc[4];
#pragma unroll
    for (int k = 0; k < 4; k++) acc[k] = make_float2(0.f, 0.f);
    for (int j = 0; j < cmax; j += 16) {
        int sarr[16];
#pragma unroll
        for (int k = 0; k < 16; k++) {
            int s = csr[min(start + j + k, cpos)];
            sarr[k] = ((j + k) < c) ? s : nodec;
        }
        float2 r[16];
#pragma unroll
        for (int k = 0; k < 16; k++) r[k] = xb[(size_t)sarr[k] * 4 + ll];
#pragma unroll
        for (int k = 0; k < 16; k++) {
            bool v = (j + k) < c;
            acc[k & 3].x += v ? r[k].x : 0.f;
            acc[k & 3].y += v ? r[k].y : 0.f;
        }
    }
    float sx = acc[0].x + acc[1].x + acc[2].x + acc[3].x;
    float sy = acc[0].y + acc[1].y + acc[2].y + acc[3].y;
    float2 self = xb[(size_t)nodec * 4 + ll];
    float dn = dis[nodec];
    sAx[ln * 9 + 2 * ll]     = dn * (sx + self.x);
    sAx[ln * 9 + 2 * ll + 1] = dn * (sy + self.y);
    __syncthreads();
    if (node < NN) {                       // epilogue: 16 out-ch per thread, 112 FMAs
        const float* axp = &sAx[ln * 9];
        union { __half h[16]; float4 f[2]; } u;
#pragma unroll
        for (int j = 0; j < 16; j++) {
            int h = ll * 16 + j;
            float a = sb[h];
#pragma unroll
            for (int k = 0; k < D_IN; k++) a += axp[k] * sW[k * H1 + h];
            u.h[j] = __float2half(dn * fmaxf(a, 0.f));
        }
        float4* d4 = (float4*)(h1h + (size_t)node * H1 + ll * 16);
        d4[0] = u.f[0];                    // 4 lanes -> 128B contiguous per node
        d4[1] = u.f[1];
    }
}

// masked packed accumulate: a[0..3] += r (as 8 halves) if v
__device__ __forceinline__ void pk_acc4(__half2* a, float4 r, bool v) {
    unsigned u0 = v ? *reinterpret_cast<unsigned*>(&r.x) : 0u;
    unsigned u1 = v ? *reinterpret_cast<unsigned*>(&r.y) : 0u;
    unsigned u2 = v ? *reinterpret_cast<unsigned*>(&r.z) : 0u;
    unsigned u3 = v ? *reinterpret_cast<unsigned*>(&r.w) : 0u;
    a[0] = __hadd2(a[0], *reinterpret_cast<__half2*>(&u0));
    a[1] = __hadd2(a[1], *reinterpret_cast<__half2*>(&u1));
    a[2] = __hadd2(a[2], *reinterpret_cast<__half2*>(&u2));
    a[3] = __hadd2(a[3], *reinterpret_cast<__half2*>(&u3));
}

// ---------------- fused layer-2: aggregate h1h, then @(W2‖W3) via MFMA + full epilogue ----------------
// Phase A: 8 lanes/node (16B float4 gathers), 8 nodes/wave-pass, 2 passes -> 16 nodes/wave.
// Explicit 16-deep register pipeline: sarr[16] (csr) -> r[16] (rows, 64 VGPR live) -> masked acc.
// Phase B: each wave MFMAs 16 rows x 64 cols (K=64, 2 steps); mu/lv pairs land in the same lane.
__global__ __launch_bounds__(256) void k_agg2f(const int2* __restrict__ rowinfo,
                                               const float* __restrict__ dis,
                                               const int* __restrict__ csr,
                                               const __half* __restrict__ h1h,
                                               const float* __restrict__ W2,
                                               const float* __restrict__ W3,
                                               const float* __restrict__ b2,
                                               const float* __restrict__ b3,
                                               const float* __restrict__ eps,
                                               float* __restrict__ out_z,
                                               float* __restrict__ out_mu,
                                               float* __restrict__ out_lv) {
    __shared__ __align__(16) _Float16 sW[64 * 80];   // Wcat [col][k], k-stride 80
    __shared__ __align__(16) _Float16 sT[64 * 72];   // s-tile [row][k], k-stride 72
    int t = threadIdx.x;
    for (int i = t; i < 64 * 64; i += 256) {
        int c = i >> 6, k = i & 63;
        float w = (c < 32) ? W2[k * H2 + c] : W3[k * H2 + (c - 32)];
        sW[c * 80 + k] = (_Float16)w;
    }
    int lane = t & 63;
    int wv = t >> 6;
    int l7 = lane & 7, sub8 = lane >> 3;
    const float4* yb4 = (const float4*)h1h;          // row = 8 float4s (128B)
    // ---- phase A: aggregation (8 lanes/node, 8 nodes/pass, 2 passes) ----
    for (int g = 0; g < 2; g++) {
        int lrow = wv * 16 + g * 8 + sub8;
        int node = blockIdx.x * 64 + lrow;
        int nodec = min(node, NN - 1);
        int2 ri = rowinfo[nodec];
        int start = ri.x, c = ri.y;
        int cpos = start + max(c - 1, 0);
        int cmax = c;                                // max degree over 8 nodes (lane bits 3..5)
        cmax = max(cmax, __shfl_xor(cmax, 8, 64));
        cmax = max(cmax, __shfl_xor(cmax, 16, 64));
        cmax = max(cmax, __shfl_xor(cmax, 32, 64));
        __half2 z2 = __float2half2_rn(0.f);
        __half2 acc[4][4];
#pragma unroll
        for (int i = 0; i < 4; i++)
#pragma unroll
            for (int k = 0; k < 4; k++) acc[i][k] = z2;
        for (int j = 0; j < cmax; j += 16) {
            int sarr[16];
#pragma unroll
            for (int k = 0; k < 16; k++) {           // 16 independent csr loads
                int s = csr[min(start + j + k, cpos)];
                sarr[k] = ((j + k) < c) ? s : nodec;
            }
            float4 r[16];
#pragma unroll
            for (int k = 0; k < 16; k++)             // 16 row gathers, all live
                r[k] = yb4[(size_t)sarr[k] * 8 + l7];
#pragma unroll
            for (int k = 0; k < 16; k++)             // masked fp16 accumulate
                pk_acc4(acc[k & 3], r[k], (j + k) < c);
        }
        __half2 s0 = __hadd2(__hadd2(acc[0][0], acc[1][0]), __hadd2(acc[2][0], acc[3][0]));
        __half2 s1 = __hadd2(__hadd2(acc[0][1], acc[1][1]), __hadd2(acc[2][1], acc[3][1]));
        __half2 s2 = __hadd2(__hadd2(acc[0][2], acc[1][2]), __hadd2(acc[2][2], acc[3][2]));
        __half2 s3 = __hadd2(__hadd2(acc[0][3], acc[1][3]), __hadd2(acc[2][3], acc[3][3]));
        float4 selfv = yb4[(size_t)nodec * 8 + l7];
        __half2* sh = reinterpret_cast<__half2*>(&selfv);
        float dn = dis[nodec];
        float2 f0 = __half22float2(s0), e0 = __half22float2(sh[0]);
        float2 f1 = __half22float2(s1), e1 = __half22float2(sh[1]);
        float2 f2 = __half22float2(s2), e2 = __half22float2(sh[2]);
        float2 f3 = __half22float2(s3), e3 = __half22float2(sh[3]);
        __half2 o0, o1, o2, o3;
        o0.x = __float2half(dn * (f0.x + e0.x)); o0.y = __float2half(dn * (f0.y + e0.y));
        o1.x = __float2half(dn * (f1.x + e1.x)); o1.y = __float2half(dn * (f1.y + e1.y));
        o2.x = __float2half(dn * (f2.x + e2.x)); o2.y = __float2half(dn * (f2.y + e2.y));
        o3.x = __float2half(dn * (f3.x + e3.x)); o3.y = __float2half(dn * (f3.y + e3.y));
        float4 st;
        st.x = *reinterpret_cast<float*>(&o0);
        st.y = *reinterpret_cast<float*>(&o1);
        st.z = *reinterpret_cast<float*>(&o2);
        st.w = *reinterpret_cast<float*>(&o3);
        *(float4*)&sT[lrow * 72 + l7 * 8] = st;      // 144B row stride, 16B aligned
    }
    __syncthreads();
    // ---- phase B: MFMA 16 rows x 64 cols per wave ----
    int sub = lane >> 4, l15 = lane & 15;
    int c15 = l15, k8 = sub;
    const _Float16* ap = &sT[(wv * 16 + c15) * 72];
    f16x8 a0 = *(const f16x8*)(ap + k8 * 8);          // A[row][k8*8 .. +8]
    f16x8 a1 = *(const f16x8*)(ap + 32 + k8 * 8);     // A[row][32 + k8*8 .. +8]
    const _Float16* wb = sW + (size_t)c15 * 80 + k8 * 8;
    f16x8 b00 = *(const f16x8*)(wb);
    f16x8 b01 = *(const f16x8*)(wb + 32);
    f16x8 b10 = *(const f16x8*)(wb + 16 * 80);
    f16x8 b11 = *(const f16x8*)(wb + 16 * 80 + 32);
    f16x8 b20 = *(const f16x8*)(wb + 32 * 80);
    f16x8 b21 = *(const f16x8*)(wb + 32 * 80 + 32);
    f16x8 b30 = *(const f16x8*)(wb + 48 * 80);
    f16x8 b31 = *(const f16x8*)(wb + 48 * 80 + 32);
    f32x4 ac0 = {0.f, 0.f, 0.f, 0.f};
    f32x4 ac1 = ac0, ac2 = ac0, ac3 = ac0;
    ac0 = __builtin_amdgcn_mfma_f32_16x16x32_f16(a0, b00, ac0, 0, 0, 0);
    ac0 = __builtin_amdgcn_mfma_f32_16x16x32_f16(a1, b01, ac0, 0, 0, 0);
    ac1 = __builtin_amdgcn_mfma_f32_16x16x32_f16(a0, b10, ac1, 0, 0, 0);
    ac1 = __builtin_amdgcn_mfma_f32_16x16x32_f16(a1, b11, ac1, 0, 0, 0);
    ac2 = __builtin_amdgcn_mfma_f32_16x16x32_f16(a0, b20, ac2, 0, 0, 0);
    ac2 = __builtin_amdgcn_mfma_f32_16x16x32_f16(a1, b21, ac2, 0, 0, 0);
    ac3 = __builtin_amdgcn_mfma_f32_16x16x32_f16(a0, b30, ac3, 0, 0, 0);
    ac3 = __builtin_amdgcn_mfma_f32_16x16x32_f16(a1, b31, ac3, 0, 0, 0);
    float bb2a = b2[c15], bb2b = b2[c15 + 16];
    float bb3a = b3[c15], bb3b = b3[c15 + 16];
    int srow = blockIdx.x * 64 + wv * 16 + k8 * 4;    // C/D: col=lane&15, row=(lane>>4)*4+reg
#pragma unroll
    for (int i = 0; i < 4; i++) {
        int r = srow + i;
        if (r < NN) {
            float mu0 = fmaxf(ac0[i] + bb2a, 0.f);
            float mu1 = fmaxf(ac1[i] + bb2b, 0.f);
            float lv0 = fmaxf(ac2[i] + bb3a, 0.f);
            float lv1 = fmaxf(ac3[i] + bb3b, 0.f);
            size_t o0 = (size_t)r * 32 + c15;
            float e0 = eps[o0], e1 = eps[o0 + 16];
            out_mu[o0]      = mu0;
            out_mu[o0 + 16] = mu1;
            out_lv[o0]      = lv0;
            out_lv[o0 + 16] = lv1;
            out_z[o0]       = e0 * __expf(lv0) + mu0;
            out_z[o0 + 16]  = e1 * __expf(lv1) + mu1;
        }
    }
}

extern "C" void kernel_launch(void* const* d_in, const int* in_sizes, int n_in,
                              void* d_out, int out_size, void* d_ws, size_t ws_size,
                              hipStream_t stream) {
    const float* x   = (const float*)d_in[0];
    const int*   ei  = (const int*)d_in[1];   // [2, E]
    const int*   bat = (const int*)d_in[2];
    const float* W1  = (const float*)d_in[3];
    const float* b1  = (const float*)d_in[4];
    const float* W2  = (const float*)d_in[5];
    const float* b2  = (const float*)d_in[6];
    const float* W3  = (const float*)d_in[7];
    const float* b3  = (const float*)d_in[8];
    const float* eps = (const float*)d_in[9];

    const int* src = ei;
    const int* dst = ei + NE;

    float* out = (float*)d_out;
    float* out_z    = out;                               // [N,32]
    float* out_pool = out + (size_t)NN * H2;             // [G,7]
    float* out_mu   = out_pool + NG * D_IN;              // [N,32]
    float* out_lv   = out_mu + (size_t)NN * H2;          // [N,32]

    // workspace layout (16B-aligned segments)
    int*    bucket_cursor = (int*)d_ws;                          // 256
    int2*   rowinfo       = (int2*)(bucket_cursor + 256);        // NN (start,cnt)
    float*  dis           = (float*)(rowinfo + NN);              // NN
    int*    staging       = (int*)(dis + NN);                    // NBUK*CAP packed ints
    int*    csr           = staging + (size_t)NBUK * CAP;        // NBUK*CAP
    __half* h1h           = (__half*)(csr + (size_t)NBUK * CAP); // NN*64 halves
    float*  xd8           = (float*)(h1h + (size_t)NN * H1);     // NN*8 fp32

    k_pi    <<<NG + 1, 256, 0, stream>>>(x, bat, out_pool, bucket_cursor);
    k_bin   <<<NTILE, 256, 0, stream>>>(src, dst, bucket_cursor, staging);
    k_build <<<NBUK, 512, 0, stream>>>(staging, bucket_cursor, rowinfo, dis, csr, x, xd8);
    k_aggx  <<<(NN + 63) / 64, 256, 0, stream>>>(rowinfo, dis, csr, xd8, W1, b1, h1h);
    k_agg2f <<<(NN + 63) / 64, 256, 0, stream>>>(rowinfo, dis, csr, h1h, W2, W3,
                                                 b2, b3, eps, out_z, out_mu, out_lv);
}